// Round 1
// baseline (8911.440 us; speedup 1.0000x reference)
//
#include <hip/hip_runtime.h>
#include <math.h>

#define NN 100000
#define E0 1600000
#define ETOT (E0 + NN)
#define NEG 0.2f

// ---------------- layer 1 node transform: x[N,4] @ W[4,64] (both l and r) ----
__global__ void k_lin1(const float* __restrict__ x, const float* __restrict__ Wl,
                       const float* __restrict__ Wr, float* __restrict__ xl,
                       float* __restrict__ xr) {
    int t = blockIdx.x * blockDim.x + threadIdx.x;
    if (t >= NN * 16) return;
    int n = t >> 4;
    int j = (t & 15) << 2;
    const float4 xv = *(const float4*)(x + n * 4);
    float xk[4] = {xv.x, xv.y, xv.z, xv.w};
    float4 al = {0.f, 0.f, 0.f, 0.f}, ar = {0.f, 0.f, 0.f, 0.f};
#pragma unroll
    for (int k = 0; k < 4; ++k) {
        float4 wl = *(const float4*)(Wl + k * 64 + j);
        float4 wr = *(const float4*)(Wr + k * 64 + j);
        al.x += xk[k] * wl.x; al.y += xk[k] * wl.y;
        al.z += xk[k] * wl.z; al.w += xk[k] * wl.w;
        ar.x += xk[k] * wr.x; ar.y += xk[k] * wr.y;
        ar.z += xk[k] * wr.z; ar.w += xk[k] * wr.w;
    }
    *(float4*)(xl + n * 64 + j) = al;
    *(float4*)(xr + n * 64 + j) = ar;
}

__device__ __forceinline__ float leaky(float v) { return v >= 0.f ? v : NEG * v; }

// ---------- layer 1 edge pass: one thread per (edge, head). heads=4, C=16 ----
__global__ void k_edge1(const int* __restrict__ ei, const float* __restrict__ xl,
                        const float* __restrict__ xr, const float* __restrict__ att,
                        float* __restrict__ denom, float* __restrict__ agg) {
    long long t = (long long)blockIdx.x * blockDim.x + threadIdx.x;
    if (t >= (long long)ETOT * 4) return;
    int e = (int)(t >> 2), h = (int)(t & 3);
    int s, d;
    if (e < E0) { s = ei[e]; d = ei[E0 + e]; } else { s = e - E0; d = s; }
    const float4* xs = (const float4*)(xl + (long long)s * 64 + h * 16);
    const float4* xd = (const float4*)(xr + (long long)d * 64 + h * 16);
    const float4* av = (const float4*)(att + h * 16);
    float4 v[4];
    float logit = 0.f;
#pragma unroll
    for (int q = 0; q < 4; ++q) {
        float4 a = xs[q], b = xd[q], w = av[q];
        v[q] = a;
        logit += leaky(a.x + b.x) * w.x;
        logit += leaky(a.y + b.y) * w.y;
        logit += leaky(a.z + b.z) * w.z;
        logit += leaky(a.w + b.w) * w.w;
    }
    float ex = __expf(logit);
    atomicAdd(denom + (long long)d * 4 + h, ex);
    float* ag = agg + (long long)d * 64 + h * 16;
#pragma unroll
    for (int q = 0; q < 4; ++q) {
        atomicAdd(ag + q * 4 + 0, ex * v[q].x);
        atomicAdd(ag + q * 4 + 1, ex * v[q].y);
        atomicAdd(ag + q * 4 + 2, ex * v[q].z);
        atomicAdd(ag + q * 4 + 3, ex * v[q].w);
    }
}

// -------- layer 1 finalize: /denom + bias -> LayerNorm(64) -> ELU, in place --
__global__ void k_node1(float* __restrict__ agg, const float* __restrict__ denom,
                        const float* __restrict__ b, const float* __restrict__ g,
                        const float* __restrict__ be) {
    int t = blockIdx.x * blockDim.x + threadIdx.x;
    int n = t >> 6;
    if (n >= NN) return;
    int lane = t & 63;
    float v = agg[(long long)n * 64 + lane] / denom[n * 4 + (lane >> 4)] + b[lane];
    float s = v;
#pragma unroll
    for (int m = 32; m; m >>= 1) s += __shfl_xor(s, m);
    float mu = s * (1.f / 64.f);
    float c = v - mu;
    float sq = c * c;
#pragma unroll
    for (int m = 32; m; m >>= 1) sq += __shfl_xor(sq, m);
    float var = sq * (1.f / 64.f);
    float y = c * rsqrtf(var + 1e-5f) * g[lane] + be[lane];
    y = y > 0.f ? y : expm1f(y);
    agg[(long long)n * 64 + lane] = y;
}

// ---------------- layer 2 node transform: h[N,64] @ W[64,32] (l and r) ------
__global__ void k_lin2(const float* __restrict__ h, const float* __restrict__ Wl,
                       const float* __restrict__ Wr, float* __restrict__ xl2,
                       float* __restrict__ xr2) {
    __shared__ float wl_s[2048];
    __shared__ float wr_s[2048];
    for (int i = threadIdx.x; i < 2048; i += blockDim.x) {
        wl_s[i] = Wl[i];
        wr_s[i] = Wr[i];
    }
    __syncthreads();
    int t = blockIdx.x * blockDim.x + threadIdx.x;
    if (t >= NN * 32) return;
    int n = t >> 5, j = t & 31;
    const float* hr = h + (long long)n * 64;
    float al = 0.f, ar = 0.f;
#pragma unroll 8
    for (int k = 0; k < 64; ++k) {
        float hv = hr[k];
        al += hv * wl_s[k * 32 + j];
        ar += hv * wr_s[k * 32 + j];
    }
    xl2[(long long)n * 32 + j] = al;
    xr2[(long long)n * 32 + j] = ar;
}

// ---------- layer 2 edge pass: one thread per edge. heads=1, C=32 -----------
__global__ void k_edge2(const int* __restrict__ ei, const float* __restrict__ xl,
                        const float* __restrict__ xr, const float* __restrict__ att,
                        float* __restrict__ denom, float* __restrict__ agg) {
    int e = blockIdx.x * blockDim.x + threadIdx.x;
    if (e >= ETOT) return;
    int s, d;
    if (e < E0) { s = ei[e]; d = ei[E0 + e]; } else { s = e - E0; d = s; }
    const float4* xs = (const float4*)(xl + (long long)s * 32);
    const float4* xd = (const float4*)(xr + (long long)d * 32);
    const float4* av = (const float4*)att;
    float4 v[8];
    float logit = 0.f;
#pragma unroll
    for (int q = 0; q < 8; ++q) {
        float4 a = xs[q], b = xd[q], w = av[q];
        v[q] = a;
        logit += leaky(a.x + b.x) * w.x;
        logit += leaky(a.y + b.y) * w.y;
        logit += leaky(a.z + b.z) * w.z;
        logit += leaky(a.w + b.w) * w.w;
    }
    float ex = __expf(logit);
    atomicAdd(denom + d, ex);
    float* ag = agg + (long long)d * 32;
#pragma unroll
    for (int q = 0; q < 8; ++q) {
        atomicAdd(ag + q * 4 + 0, ex * v[q].x);
        atomicAdd(ag + q * 4 + 1, ex * v[q].y);
        atomicAdd(ag + q * 4 + 2, ex * v[q].z);
        atomicAdd(ag + q * 4 + 3, ex * v[q].w);
    }
}

// -------- layer 2 finalize: /denom + bias -> LayerNorm(32) -> out -----------
__global__ void k_node2(const float* __restrict__ agg, const float* __restrict__ denom,
                        const float* __restrict__ b, const float* __restrict__ g,
                        const float* __restrict__ be, float* __restrict__ out) {
    int t = blockIdx.x * blockDim.x + threadIdx.x;
    int n = t >> 5;
    if (n >= NN) return;
    int c = t & 31;
    float v = agg[(long long)n * 32 + c] / denom[n] + b[c];
    float s = v;
#pragma unroll
    for (int m = 16; m; m >>= 1) s += __shfl_xor(s, m, 32);
    float mu = s * (1.f / 32.f);
    float cc = v - mu;
    float sq = cc * cc;
#pragma unroll
    for (int m = 16; m; m >>= 1) sq += __shfl_xor(sq, m, 32);
    float var = sq * (1.f / 32.f);
    out[(long long)n * 32 + c] = cc * rsqrtf(var + 1e-5f) * g[c] + be[c];
}

extern "C" void kernel_launch(void* const* d_in, const int* in_sizes, int n_in,
                              void* d_out, int out_size, void* d_ws, size_t ws_size,
                              hipStream_t stream) {
    const float* x   = (const float*)d_in[0];
    const int*   ei  = (const int*)d_in[1];
    const float* W1l = (const float*)d_in[2];
    const float* W1r = (const float*)d_in[3];
    const float* a1  = (const float*)d_in[4];
    const float* b1  = (const float*)d_in[5];
    const float* g1  = (const float*)d_in[6];
    const float* be1 = (const float*)d_in[7];
    const float* W2l = (const float*)d_in[8];
    const float* W2r = (const float*)d_in[9];
    const float* a2  = (const float*)d_in[10];
    const float* b2  = (const float*)d_in[11];
    const float* g2  = (const float*)d_in[12];
    const float* be2 = (const float*)d_in[13];
    float* out = (float*)d_out;

    float* ws = (float*)d_ws;
    float* xl1    = ws;             // N*64 = 6.4M floats
    float* xr1    = ws + 6400000;   // N*64
    float* agg1   = ws + 12800000;  // N*64 (becomes h after k_node1)
    float* denom1 = ws + 19200000;  // N*4
    // layer-2 reuse:
    float* xl2    = ws;             // N*32 (first half of xl1 region)
    float* agg2   = ws + 3200000;   // N*32 (second half of xl1 region)
    float* xr2    = xr1;            // N*32
    float* denom2 = denom1;         // N

    hipMemsetAsync(denom1, 0, (size_t)NN * 4 * sizeof(float), stream);
    hipMemsetAsync(agg1, 0, (size_t)NN * 64 * sizeof(float), stream);

    k_lin1<<<(NN * 16 + 255) / 256, 256, 0, stream>>>(x, W1l, W1r, xl1, xr1);
    k_edge1<<<((long long)ETOT * 4 + 255) / 256, 256, 0, stream>>>(ei, xl1, xr1, a1,
                                                                   denom1, agg1);
    k_node1<<<(NN * 64 + 255) / 256, 256, 0, stream>>>(agg1, denom1, b1, g1, be1);

    k_lin2<<<(NN * 32 + 255) / 256, 256, 0, stream>>>(agg1, W2l, W2r, xl2, xr2);
    hipMemsetAsync(denom2, 0, (size_t)NN * sizeof(float), stream);
    hipMemsetAsync(agg2, 0, (size_t)NN * 32 * sizeof(float), stream);
    k_edge2<<<(ETOT + 255) / 256, 256, 0, stream>>>(ei, xl2, xr2, a2, denom2, agg2);
    k_node2<<<(NN * 32 + 255) / 256, 256, 0, stream>>>(agg2, denom2, b2, g2, be2, out);
}

// Round 2
// 497.501 us; speedup vs baseline: 17.9124x; 17.9124x over previous
//
#include <hip/hip_runtime.h>
#include <math.h>

#define NN 100000
#define E0 1600000
#define ETOT (E0 + NN)
#define NEG 0.2f

// ---------------- CSR build: histogram over dst ----------------------------
__global__ void k_hist(const int* __restrict__ ei, int* __restrict__ cursor) {
    int e = blockIdx.x * blockDim.x + threadIdx.x;
    if (e < E0) atomicAdd(cursor + ei[E0 + e], 1);
}

// scan pass 1: per-1024-block exclusive scan of (deg+1); block sums out
__global__ void k_scan1(const int* __restrict__ deg, int* __restrict__ rs,
                        int* __restrict__ bsum) {
    __shared__ int s[1024];
    int tid = threadIdx.x, gid = blockIdx.x * 1024 + tid;
    int v = (gid < NN) ? deg[gid] + 1 : 0;  // +1 = self-loop
    s[tid] = v;
    __syncthreads();
    for (int off = 1; off < 1024; off <<= 1) {
        int t = (tid >= off) ? s[tid - off] : 0;
        __syncthreads();
        s[tid] += t;
        __syncthreads();
    }
    if (gid < NN) rs[gid] = s[tid] - v;  // exclusive within block
    if (tid == 1023) bsum[blockIdx.x] = s[1023];
}

// scan pass 2: exclusive scan of 98 block sums (single block)
__global__ void k_scan2(int* __restrict__ bsum) {
    __shared__ int s[128];
    int tid = threadIdx.x;
    int v = (tid < 98) ? bsum[tid] : 0;
    s[tid] = v;
    __syncthreads();
    for (int off = 1; off < 128; off <<= 1) {
        int t = (tid >= off) ? s[tid - off] : 0;
        __syncthreads();
        s[tid] += t;
        __syncthreads();
    }
    if (tid < 98) bsum[tid] = s[tid] - v;
}

// scan pass 3: finalize row_start; place self-loop; init cursor past it
__global__ void k_scan3(int* __restrict__ rs, const int* __restrict__ bsum,
                        int* __restrict__ cursor, int* __restrict__ srcs) {
    int gid = blockIdx.x * blockDim.x + threadIdx.x;
    if (gid >= NN) return;
    int r = rs[gid] + bsum[gid >> 10];
    rs[gid] = r;
    srcs[r] = gid;       // self-loop occupies first slot of each segment
    cursor[gid] = r + 1;
}

// scatter real edges into dst-sorted src list
__global__ void k_scatter(const int* __restrict__ ei, int* __restrict__ cursor,
                          int* __restrict__ srcs) {
    int e = blockIdx.x * blockDim.x + threadIdx.x;
    if (e >= E0) return;
    int d = ei[E0 + e];
    int pos = atomicAdd(cursor + d, 1);
    srcs[pos] = ei[e];
}

// ---------------- layer 1 source transform: x[N,4] @ W1l[4,64] --------------
__global__ void k_lin1(const float* __restrict__ x, const float* __restrict__ Wl,
                       float* __restrict__ xl) {
    int t = blockIdx.x * blockDim.x + threadIdx.x;
    if (t >= NN * 16) return;
    int n = t >> 4;
    int j = (t & 15) << 2;
    const float4 xv = *(const float4*)(x + n * 4);
    float xk[4] = {xv.x, xv.y, xv.z, xv.w};
    float4 a = {0.f, 0.f, 0.f, 0.f};
#pragma unroll
    for (int k = 0; k < 4; ++k) {
        float4 w = *(const float4*)(Wl + k * 64 + j);
        a.x += xk[k] * w.x; a.y += xk[k] * w.y;
        a.z += xk[k] * w.z; a.w += xk[k] * w.w;
    }
    *(float4*)(xl + n * 64 + j) = a;
}

// ------ layer 1 gather: one wave per node; lane = (head<<4)|chan ------------
// fused: xr on the fly, softmax (shift-free), /den + bias, LN(64), ELU
__global__ void k_gat1(const float* __restrict__ x, const float* __restrict__ Wr,
                       const float* __restrict__ att, const float* __restrict__ xl,
                       const int* __restrict__ rs, const int* __restrict__ srcs,
                       const float* __restrict__ b, const float* __restrict__ g,
                       const float* __restrict__ be, float* __restrict__ h) {
    int n = blockIdx.x * (blockDim.x >> 6) + (threadIdx.x >> 6);
    if (n >= NN) return;
    int lane = threadIdx.x & 63;
    const float4 xd = *(const float4*)(x + n * 4);
    float xrd = xd.x * Wr[lane] + xd.y * Wr[64 + lane] + xd.z * Wr[128 + lane] +
                xd.w * Wr[192 + lane];
    float attl = att[lane];
    int beg = rs[n];
    int end = (n == NN - 1) ? ETOT : rs[n + 1];
    float acc = 0.f, den = 0.f;
    int base = beg;
    while (base < end) {
        int cnt = end - base;
        if (cnt > 64) cnt = 64;
        int si = (lane < cnt) ? srcs[base + lane] : 0;
        for (int j = 0; j < cnt; ++j) {
            int s = __shfl(si, j);
            float xls = xl[(long long)s * 64 + lane];
            float t = xls + xrd;
            t = t >= 0.f ? t : NEG * t;
            t *= attl;
            t += __shfl_xor(t, 1);
            t += __shfl_xor(t, 2);
            t += __shfl_xor(t, 4);
            t += __shfl_xor(t, 8);
            float ex = __expf(t);
            acc += ex * xls;
            den += ex;
        }
        base += cnt;
    }
    float v = acc / den + b[lane];
    float s1 = v;
#pragma unroll
    for (int m = 1; m < 64; m <<= 1) s1 += __shfl_xor(s1, m);
    float mu = s1 * (1.f / 64.f);
    float c = v - mu;
    float sq = c * c;
#pragma unroll
    for (int m = 1; m < 64; m <<= 1) sq += __shfl_xor(sq, m);
    float y = c * rsqrtf(sq * (1.f / 64.f) + 1e-5f) * g[lane] + be[lane];
    h[(long long)n * 64 + lane] = y > 0.f ? y : expm1f(y);
}

// ---------------- layer 2 node transform: h[N,64] @ W[64,32] (l and r) ------
__global__ void k_lin2(const float* __restrict__ h, const float* __restrict__ Wl,
                       const float* __restrict__ Wr, float* __restrict__ xl2,
                       float* __restrict__ xr2) {
    __shared__ float wl_s[2048];
    __shared__ float wr_s[2048];
    for (int i = threadIdx.x; i < 2048; i += blockDim.x) {
        wl_s[i] = Wl[i];
        wr_s[i] = Wr[i];
    }
    __syncthreads();
    int t = blockIdx.x * blockDim.x + threadIdx.x;
    if (t >= NN * 32) return;
    int n = t >> 5, j = t & 31;
    const float* hr = h + (long long)n * 64;
    float al = 0.f, ar = 0.f;
#pragma unroll 8
    for (int k = 0; k < 64; ++k) {
        float hv = hr[k];
        al += hv * wl_s[k * 32 + j];
        ar += hv * wr_s[k * 32 + j];
    }
    xl2[(long long)n * 32 + j] = al;
    xr2[(long long)n * 32 + j] = ar;
}

// ------ layer 2 gather: one wave per node; 2 edges/iter (half = lane>>5) ----
__global__ void k_gat2(const float* __restrict__ xl2, const float* __restrict__ xr2,
                       const float* __restrict__ att, const int* __restrict__ rs,
                       const int* __restrict__ srcs, const float* __restrict__ b,
                       const float* __restrict__ g, const float* __restrict__ be,
                       float* __restrict__ out) {
    int n = blockIdx.x * (blockDim.x >> 6) + (threadIdx.x >> 6);
    if (n >= NN) return;
    int lane = threadIdx.x & 63;
    int half = lane >> 5, c = lane & 31;
    float xrd = xr2[(long long)n * 32 + c];
    float attl = att[c];
    int beg = rs[n];
    int end = (n == NN - 1) ? ETOT : rs[n + 1];
    float acc = 0.f, den = 0.f;
    int base = beg;
    while (base < end) {
        int cnt = end - base;
        if (cnt > 64) cnt = 64;
        int si = (lane < cnt) ? srcs[base + lane] : 0;
        int nit = (cnt + 1) >> 1;
        for (int j = 0; j < nit; ++j) {
            int idx = j * 2 + half;
            bool valid = idx < cnt;
            int s = __shfl(si, valid ? idx : 0);
            float xls = xl2[(long long)s * 32 + c];
            float t = xls + xrd;
            t = t >= 0.f ? t : NEG * t;
            t *= attl;
            t += __shfl_xor(t, 1);
            t += __shfl_xor(t, 2);
            t += __shfl_xor(t, 4);
            t += __shfl_xor(t, 8);
            t += __shfl_xor(t, 16);
            float ex = valid ? __expf(t) : 0.f;
            acc += ex * xls;
            den += ex;
        }
        base += cnt;
    }
    acc += __shfl_xor(acc, 32);
    den += __shfl_xor(den, 32);
    float v = acc / den + b[c];
    float s1 = v;
#pragma unroll
    for (int m = 1; m < 32; m <<= 1) s1 += __shfl_xor(s1, m);
    float mu = s1 * (1.f / 32.f);
    float cc = v - mu;
    float sq = cc * cc;
#pragma unroll
    for (int m = 1; m < 32; m <<= 1) sq += __shfl_xor(sq, m);
    float y = cc * rsqrtf(sq * (1.f / 32.f) + 1e-5f) * g[c] + be[c];
    if (half == 0) out[(long long)n * 32 + c] = y;
}

extern "C" void kernel_launch(void* const* d_in, const int* in_sizes, int n_in,
                              void* d_out, int out_size, void* d_ws, size_t ws_size,
                              hipStream_t stream) {
    const float* x   = (const float*)d_in[0];
    const int*   ei  = (const int*)d_in[1];
    const float* W1l = (const float*)d_in[2];
    const float* W1r = (const float*)d_in[3];
    const float* a1  = (const float*)d_in[4];
    const float* b1  = (const float*)d_in[5];
    const float* g1  = (const float*)d_in[6];
    const float* be1 = (const float*)d_in[7];
    const float* W2l = (const float*)d_in[8];
    const float* W2r = (const float*)d_in[9];
    const float* a2  = (const float*)d_in[10];
    const float* b2  = (const float*)d_in[11];
    const float* g2  = (const float*)d_in[12];
    const float* be2 = (const float*)d_in[13];
    float* out = (float*)d_out;

    float* ws = (float*)d_ws;
    float* xl1 = ws;             // N*64 floats (layer-1 source features)
    float* h   = ws + 6400000;   // N*64 floats (layer-1 output)
    float* xl2 = ws;             // N*32 (reuse xl1 region after k_gat1)
    float* xr2 = ws + 3200000;   // N*32
    int* ib        = (int*)(ws + 12800000);
    int* row_start = ib;              // NN (+1 pad)
    int* cursor    = ib + 100001;     // NN
    int* srcs      = ib + 200002;     // ETOT = 1.7M
    int* bsum      = ib + 1900002;    // 128

    // ---- CSR build (shared by both layers) ----
    hipMemsetAsync(cursor, 0, (size_t)NN * sizeof(int), stream);
    k_hist<<<(E0 + 255) / 256, 256, 0, stream>>>(ei, cursor);
    k_scan1<<<98, 1024, 0, stream>>>(cursor, row_start, bsum);
    k_scan2<<<1, 128, 0, stream>>>(bsum);
    k_scan3<<<(NN + 255) / 256, 256, 0, stream>>>(row_start, bsum, cursor, srcs);
    k_scatter<<<(E0 + 255) / 256, 256, 0, stream>>>(ei, cursor, srcs);

    // ---- layer 1 ----
    k_lin1<<<(NN * 16 + 255) / 256, 256, 0, stream>>>(x, W1l, xl1);
    k_gat1<<<(NN + 3) / 4, 256, 0, stream>>>(x, W1r, a1, xl1, row_start, srcs,
                                             b1, g1, be1, h);
    // ---- layer 2 ----
    k_lin2<<<(NN * 32 + 255) / 256, 256, 0, stream>>>(h, W2l, W2r, xl2, xr2);
    k_gat2<<<(NN + 3) / 4, 256, 0, stream>>>(xl2, xr2, a2, row_start, srcs,
                                             b2, g2, be2, out);
}

// Round 3
// 410.836 us; speedup vs baseline: 21.6910x; 1.2109x over previous
//
#include <hip/hip_runtime.h>
#include <math.h>

#define NN 100000
#define E0 1600000
#define ETOT (E0 + NN)
#define NEG 0.2f

__device__ __forceinline__ float leaky(float v) { return fmaxf(v, NEG * v); }

// ---------------- CSR build: histogram over dst ----------------------------
__global__ void k_hist(const int* __restrict__ ei, int* __restrict__ cursor) {
    int e = blockIdx.x * blockDim.x + threadIdx.x;
    if (e < E0) atomicAdd(cursor + ei[E0 + e], 1);
}

// scan pass 1: per-1024-block exclusive scan of (deg+1); block sums out
__global__ void k_scan1(const int* __restrict__ deg, int* __restrict__ rs,
                        int* __restrict__ bsum) {
    __shared__ int s[1024];
    int tid = threadIdx.x, gid = blockIdx.x * 1024 + tid;
    int v = (gid < NN) ? deg[gid] + 1 : 0;  // +1 = self-loop
    s[tid] = v;
    __syncthreads();
    for (int off = 1; off < 1024; off <<= 1) {
        int t = (tid >= off) ? s[tid - off] : 0;
        __syncthreads();
        s[tid] += t;
        __syncthreads();
    }
    if (gid < NN) rs[gid] = s[tid] - v;  // exclusive within block
    if (tid == 1023) bsum[blockIdx.x] = s[1023];
}

// scan pass 2: exclusive scan of 98 block sums (single block)
__global__ void k_scan2(int* __restrict__ bsum) {
    __shared__ int s[128];
    int tid = threadIdx.x;
    int v = (tid < 98) ? bsum[tid] : 0;
    s[tid] = v;
    __syncthreads();
    for (int off = 1; off < 128; off <<= 1) {
        int t = (tid >= off) ? s[tid - off] : 0;
        __syncthreads();
        s[tid] += t;
        __syncthreads();
    }
    if (tid < 98) bsum[tid] = s[tid] - v;
}

// scan pass 3: finalize row_start; place self-loop; init cursor past it
__global__ void k_scan3(int* __restrict__ rs, const int* __restrict__ bsum,
                        int* __restrict__ cursor, int* __restrict__ srcs) {
    int gid = blockIdx.x * blockDim.x + threadIdx.x;
    if (gid >= NN) return;
    int r = rs[gid] + bsum[gid >> 10];
    rs[gid] = r;
    srcs[r] = gid;       // self-loop occupies first slot of each segment
    cursor[gid] = r + 1;
}

// scatter real edges into dst-sorted src list
__global__ void k_scatter(const int* __restrict__ ei, int* __restrict__ cursor,
                          int* __restrict__ srcs) {
    int e = blockIdx.x * blockDim.x + threadIdx.x;
    if (e >= E0) return;
    int d = ei[E0 + e];
    int pos = atomicAdd(cursor + d, 1);
    srcs[pos] = ei[e];
}

// ------ layer 1 gather: one wave per node; lane = (head<<4)|chan ------------
// xl recomputed from raw x (rank-4): 16B L2-resident gather per edge.
// fused: xr on the fly, softmax (shift-free), /den + bias, LN(64), ELU
__global__ void k_gat1(const float* __restrict__ x, const float* __restrict__ Wl,
                       const float* __restrict__ Wr, const float* __restrict__ att,
                       const int* __restrict__ rs, const int* __restrict__ srcs,
                       const float* __restrict__ b, const float* __restrict__ g,
                       const float* __restrict__ be, float* __restrict__ h) {
    int n = blockIdx.x * (blockDim.x >> 6) + (threadIdx.x >> 6);
    if (n >= NN) return;
    int lane = threadIdx.x & 63;
    float wl0 = Wl[lane], wl1 = Wl[64 + lane], wl2 = Wl[128 + lane],
          wl3 = Wl[192 + lane];
    const float4 xd = *(const float4*)(x + n * 4);
    float xrd = xd.x * Wr[lane] + xd.y * Wr[64 + lane] + xd.z * Wr[128 + lane] +
                xd.w * Wr[192 + lane];
    float attl = att[lane];
    int beg = rs[n];
    int end = (n == NN - 1) ? ETOT : rs[n + 1];
    float acc = 0.f, den = 0.f;
    int base = beg;
    while (base < end) {
        int cnt = end - base;
        if (cnt > 64) cnt = 64;
        int si = (lane < cnt) ? srcs[base + lane] : 0;
        int j = 0;
        for (; j + 2 <= cnt; j += 2) {
            int s0 = __builtin_amdgcn_readlane(si, j);
            int s1 = __builtin_amdgcn_readlane(si, j + 1);
            const float4 xa = *(const float4*)(x + s0 * 4);
            const float4 xb = *(const float4*)(x + s1 * 4);
            float xlsa = xa.x * wl0 + xa.y * wl1 + xa.z * wl2 + xa.w * wl3;
            float xlsb = xb.x * wl0 + xb.y * wl1 + xb.z * wl2 + xb.w * wl3;
            float ta = leaky(xlsa + xrd) * attl;
            float tb = leaky(xlsb + xrd) * attl;
            ta += __shfl_xor(ta, 1); tb += __shfl_xor(tb, 1);
            ta += __shfl_xor(ta, 2); tb += __shfl_xor(tb, 2);
            ta += __shfl_xor(ta, 4); tb += __shfl_xor(tb, 4);
            ta += __shfl_xor(ta, 8); tb += __shfl_xor(tb, 8);
            float exa = __expf(ta), exb = __expf(tb);
            acc += exa * xlsa;
            acc += exb * xlsb;
            den += exa + exb;
        }
        if (j < cnt) {
            int s0 = __builtin_amdgcn_readlane(si, j);
            const float4 xa = *(const float4*)(x + s0 * 4);
            float xlsa = xa.x * wl0 + xa.y * wl1 + xa.z * wl2 + xa.w * wl3;
            float ta = leaky(xlsa + xrd) * attl;
            ta += __shfl_xor(ta, 1);
            ta += __shfl_xor(ta, 2);
            ta += __shfl_xor(ta, 4);
            ta += __shfl_xor(ta, 8);
            float exa = __expf(ta);
            acc += exa * xlsa;
            den += exa;
        }
        base += cnt;
    }
    float v = acc / den + b[lane];
    float s1 = v;
#pragma unroll
    for (int m = 1; m < 64; m <<= 1) s1 += __shfl_xor(s1, m);
    float mu = s1 * (1.f / 64.f);
    float c = v - mu;
    float sq = c * c;
#pragma unroll
    for (int m = 1; m < 64; m <<= 1) sq += __shfl_xor(sq, m);
    float y = c * rsqrtf(sq * (1.f / 64.f) + 1e-5f) * g[lane] + be[lane];
    h[(long long)n * 64 + lane] = y > 0.f ? y : expm1f(y);
}

// ---------------- layer 2 node transform: h[N,64] @ W[64,32] (l and r) ------
__global__ void k_lin2(const float* __restrict__ h, const float* __restrict__ Wl,
                       const float* __restrict__ Wr, float* __restrict__ xl2,
                       float* __restrict__ xr2) {
    __shared__ float wl_s[2048];
    __shared__ float wr_s[2048];
    for (int i = threadIdx.x; i < 2048; i += blockDim.x) {
        wl_s[i] = Wl[i];
        wr_s[i] = Wr[i];
    }
    __syncthreads();
    int t = blockIdx.x * blockDim.x + threadIdx.x;
    if (t >= NN * 32) return;
    int n = t >> 5, j = t & 31;
    const float* hr = h + (long long)n * 64;
    float al = 0.f, ar = 0.f;
#pragma unroll 8
    for (int k = 0; k < 64; ++k) {
        float hv = hr[k];
        al += hv * wl_s[k * 32 + j];
        ar += hv * wr_s[k * 32 + j];
    }
    xl2[(long long)n * 32 + j] = al;
    xr2[(long long)n * 32 + j] = ar;
}

// ------ layer 2 gather: one wave per node; 2 edges/iter via halves, x2 unroll
__global__ void k_gat2(const float* __restrict__ xl2, const float* __restrict__ xr2,
                       const float* __restrict__ att, const int* __restrict__ rs,
                       const int* __restrict__ srcs, const float* __restrict__ b,
                       const float* __restrict__ g, const float* __restrict__ be,
                       float* __restrict__ out) {
    int n = blockIdx.x * (blockDim.x >> 6) + (threadIdx.x >> 6);
    if (n >= NN) return;
    int lane = threadIdx.x & 63;
    int half = lane >> 5, c = lane & 31;
    float xrd = xr2[(long long)n * 32 + c];
    float attl = att[c];
    int beg = rs[n];
    int end = (n == NN - 1) ? ETOT : rs[n + 1];
    float acc = 0.f, den = 0.f;
    int base = beg;
    while (base < end) {
        int cnt = end - base;
        if (cnt > 64) cnt = 64;
        int si = (lane < cnt) ? srcs[base + lane] : 0;
        int nit = (cnt + 1) >> 1;  // pair-iterations
        int j = 0;
        for (; j + 2 <= nit; j += 2) {
            int i0 = j * 2 + half, i1 = (j + 1) * 2 + half;
            bool v0 = i0 < cnt, v1 = i1 < cnt;
            int s0 = __shfl(si, v0 ? i0 : 0);
            int s1 = __shfl(si, v1 ? i1 : 0);
            float xlsa = xl2[(long long)s0 * 32 + c];
            float xlsb = xl2[(long long)s1 * 32 + c];
            float ta = leaky(xlsa + xrd) * attl;
            float tb = leaky(xlsb + xrd) * attl;
            ta += __shfl_xor(ta, 1);  tb += __shfl_xor(tb, 1);
            ta += __shfl_xor(ta, 2);  tb += __shfl_xor(tb, 2);
            ta += __shfl_xor(ta, 4);  tb += __shfl_xor(tb, 4);
            ta += __shfl_xor(ta, 8);  tb += __shfl_xor(tb, 8);
            ta += __shfl_xor(ta, 16); tb += __shfl_xor(tb, 16);
            float exa = v0 ? __expf(ta) : 0.f;
            float exb = v1 ? __expf(tb) : 0.f;
            acc += exa * xlsa;
            acc += exb * xlsb;
            den += exa + exb;
        }
        if (j < nit) {
            int i0 = j * 2 + half;
            bool v0 = i0 < cnt;
            int s0 = __shfl(si, v0 ? i0 : 0);
            float xlsa = xl2[(long long)s0 * 32 + c];
            float ta = leaky(xlsa + xrd) * attl;
            ta += __shfl_xor(ta, 1);
            ta += __shfl_xor(ta, 2);
            ta += __shfl_xor(ta, 4);
            ta += __shfl_xor(ta, 8);
            ta += __shfl_xor(ta, 16);
            float exa = v0 ? __expf(ta) : 0.f;
            acc += exa * xlsa;
            den += exa;
        }
        base += cnt;
    }
    acc += __shfl_xor(acc, 32);
    den += __shfl_xor(den, 32);
    float v = acc / den + b[c];
    float s1 = v;
#pragma unroll
    for (int m = 1; m < 32; m <<= 1) s1 += __shfl_xor(s1, m);
    float mu = s1 * (1.f / 32.f);
    float cc = v - mu;
    float sq = cc * cc;
#pragma unroll
    for (int m = 1; m < 32; m <<= 1) sq += __shfl_xor(sq, m);
    float y = cc * rsqrtf(sq * (1.f / 32.f) + 1e-5f) * g[c] + be[c];
    if (half == 0) out[(long long)n * 32 + c] = y;
}

extern "C" void kernel_launch(void* const* d_in, const int* in_sizes, int n_in,
                              void* d_out, int out_size, void* d_ws, size_t ws_size,
                              hipStream_t stream) {
    const float* x   = (const float*)d_in[0];
    const int*   ei  = (const int*)d_in[1];
    const float* W1l = (const float*)d_in[2];
    const float* W1r = (const float*)d_in[3];
    const float* a1  = (const float*)d_in[4];
    const float* b1  = (const float*)d_in[5];
    const float* g1  = (const float*)d_in[6];
    const float* be1 = (const float*)d_in[7];
    const float* W2l = (const float*)d_in[8];
    const float* W2r = (const float*)d_in[9];
    const float* a2  = (const float*)d_in[10];
    const float* b2  = (const float*)d_in[11];
    const float* g2  = (const float*)d_in[12];
    const float* be2 = (const float*)d_in[13];
    float* out = (float*)d_out;

    float* ws = (float*)d_ws;
    float* h   = ws;             // N*64 floats (layer-1 output)
    float* xl2 = ws + 6400000;   // N*32
    float* xr2 = ws + 9600000;   // N*32
    int* ib        = (int*)(ws + 12800000);
    int* row_start = ib;              // NN (+1 pad)
    int* cursor    = ib + 100001;     // NN
    int* srcs      = ib + 200002;     // ETOT = 1.7M
    int* bsum      = ib + 1900002;    // 128

    // ---- CSR build (shared by both layers) ----
    hipMemsetAsync(cursor, 0, (size_t)NN * sizeof(int), stream);
    k_hist<<<(E0 + 255) / 256, 256, 0, stream>>>(ei, cursor);
    k_scan1<<<98, 1024, 0, stream>>>(cursor, row_start, bsum);
    k_scan2<<<1, 128, 0, stream>>>(bsum);
    k_scan3<<<(NN + 255) / 256, 256, 0, stream>>>(row_start, bsum, cursor, srcs);
    k_scatter<<<(E0 + 255) / 256, 256, 0, stream>>>(ei, cursor, srcs);

    // ---- layer 1 (xl recomputed from x in-wave; no k_lin1) ----
    k_gat1<<<(NN + 3) / 4, 256, 0, stream>>>(x, W1l, W1r, a1, row_start, srcs,
                                             b1, g1, be1, h);
    // ---- layer 2 ----
    k_lin2<<<(NN * 32 + 255) / 256, 256, 0, stream>>>(h, W2l, W2r, xl2, xr2);
    k_gat2<<<(NN + 3) / 4, 256, 0, stream>>>(xl2, xr2, a2, row_start, srcs,
                                             b2, g2, be2, out);
}

// Round 4
// 260.415 us; speedup vs baseline: 34.2201x; 1.5776x over previous
//
#include <hip/hip_runtime.h>
#include <math.h>

#define NN 100000
#define E0 1600000
#define ETOT (E0 + NN)
#define NEG 0.2f

#define NB 512          // dst buckets
#define BS 196          // nodes per bucket (NB*BS >= NN)
#define CHUNK 4096      // edges per k_bin block
#define PPT 16          // pairs per thread
#define MAXP 4096       // max pairs per bucket (mean 3136, sigma 56)

__device__ __forceinline__ float leaky(float v) { return fmaxf(v, NEG * v); }

// ---- pass A: bucket histogram (LDS-aggregated) -----------------------------
__global__ void k_bhist(const int* __restrict__ ei, int* __restrict__ bcnt) {
    __shared__ int h[NB];
    int tid = threadIdx.x;
    for (int i = tid; i < NB; i += 256) h[i] = 0;
    __syncthreads();
    int stride = gridDim.x * 256;
    for (int e = blockIdx.x * 256 + tid; e < E0; e += stride)
        atomicAdd(&h[ei[E0 + e] / BS], 1);
    __syncthreads();
    for (int i = tid; i < NB; i += 256)
        if (h[i]) atomicAdd(&bcnt[i], h[i]);
}

// ---- pass B: scan bucket counts --------------------------------------------
__global__ void k_bscan(const int* __restrict__ bcnt, int* __restrict__ boff,
                        int* __restrict__ srcsBase, int* __restrict__ cursor) {
    __shared__ int s[NB];
    int tid = threadIdx.x;
    int v = bcnt[tid];
    s[tid] = v;
    __syncthreads();
    for (int off = 1; off < NB; off <<= 1) {
        int t = (tid >= off) ? s[tid - off] : 0;
        __syncthreads();
        s[tid] += t;
        __syncthreads();
    }
    int excl = s[tid] - v;
    boff[tid] = excl;
    cursor[tid] = excl;
    int n0 = tid * BS;
    if (n0 > NN) n0 = NN;
    srcsBase[tid] = excl + n0;  // + self-loops of all earlier nodes
}

// ---- pass C: bin edges into bucket-sorted pair array (run-aggregated) ------
__global__ void k_bin(const int* __restrict__ ei, int* __restrict__ cursor,
                      int2* __restrict__ binned) {
    __shared__ int hist[NB];
    __shared__ int basesh[NB];
    int tid = threadIdx.x;
    long long cbase = (long long)blockIdx.x * CHUNK;
    for (int i = tid; i < NB; i += 256) hist[i] = 0;
    __syncthreads();
    int srcv[PPT], dstv[PPT], rank[PPT], bkt[PPT];
#pragma unroll
    for (int k = 0; k < PPT; ++k) {
        long long e = cbase + k * 256 + tid;
        if (e < E0) {
            int s_ = ei[e];
            int d_ = ei[E0 + e];
            int b = d_ / BS;
            rank[k] = atomicAdd(&hist[b], 1);
            srcv[k] = s_;
            dstv[k] = d_;
            bkt[k] = b;
        } else {
            bkt[k] = -1;
        }
    }
    __syncthreads();
    for (int i = tid; i < NB; i += 256)
        if (hist[i] > 0) basesh[i] = atomicAdd(&cursor[i], hist[i]);
    __syncthreads();
#pragma unroll
    for (int k = 0; k < PPT; ++k)
        if (bkt[k] >= 0) {
            int2 p;
            p.x = srcv[k];
            p.y = dstv[k];
            binned[basesh[bkt[k]] + rank[k]] = p;
        }
}

// ---- pass D: per-bucket finalize: row_start + dst-sorted srcs (coalesced) --
__global__ void k_bfin(const int2* __restrict__ binned, const int* __restrict__ bcnt,
                       const int* __restrict__ boff, const int* __restrict__ srcsBase,
                       int* __restrict__ rs, int* __restrict__ srcs) {
    int b = blockIdx.x;
    int n0 = b * BS;
    if (n0 >= NN) return;
    int nd = NN - n0;
    if (nd > BS) nd = BS;
    int cnt = bcnt[b];
    if (cnt > MAXP) cnt = MAXP;  // statistically impossible; safety
    int base = boff[b];
    int sb = srcsBase[b];
    __shared__ int ldsCnt[256];
    __shared__ int scanA[256];
    __shared__ int rowOffE[256];
    __shared__ int stage[MAXP + BS];
    int tid = threadIdx.x;
    ldsCnt[tid] = 0;
    __syncthreads();
    int srcv[PPT], dl_[PPT], rk_[PPT];
#pragma unroll
    for (int k = 0; k < PPT; ++k) {
        int i = k * 256 + tid;
        if (i < cnt) {
            int2 p = binned[base + i];
            int dl = p.y - n0;
            rk_[k] = atomicAdd(&ldsCnt[dl], 1);
            srcv[k] = p.x;
            dl_[k] = dl;
        } else {
            dl_[k] = -1;
        }
    }
    __syncthreads();
    int v = (tid < nd) ? ldsCnt[tid] + 1 : 0;  // +1 self-loop
    scanA[tid] = v;
    __syncthreads();
    for (int off = 1; off < 256; off <<= 1) {
        int t = (tid >= off) ? scanA[tid - off] : 0;
        __syncthreads();
        scanA[tid] += t;
        __syncthreads();
    }
    rowOffE[tid] = scanA[tid] - v;
    __syncthreads();
    if (tid < nd) {
        int e = rowOffE[tid];
        rs[n0 + tid] = sb + e;
        stage[e] = n0 + tid;  // self-loop occupies first slot
    }
    __syncthreads();
#pragma unroll
    for (int k = 0; k < PPT; ++k)
        if (dl_[k] >= 0) stage[rowOffE[dl_[k]] + 1 + rk_[k]] = srcv[k];
    __syncthreads();
    int tot = cnt + nd;
    for (int i = tid; i < tot; i += 256) srcs[sb + i] = stage[i];
}

// ------ layer 1 gather: one wave per node; lane = (head<<4)|chan ------------
__global__ void k_gat1(const float* __restrict__ x, const float* __restrict__ Wl,
                       const float* __restrict__ Wr, const float* __restrict__ att,
                       const int* __restrict__ rs, const int* __restrict__ srcs,
                       const float* __restrict__ b, const float* __restrict__ g,
                       const float* __restrict__ be, float* __restrict__ h) {
    int n = blockIdx.x * (blockDim.x >> 6) + (threadIdx.x >> 6);
    if (n >= NN) return;
    int lane = threadIdx.x & 63;
    float wl0 = Wl[lane], wl1 = Wl[64 + lane], wl2 = Wl[128 + lane],
          wl3 = Wl[192 + lane];
    const float4 xd = *(const float4*)(x + n * 4);
    float xrd = xd.x * Wr[lane] + xd.y * Wr[64 + lane] + xd.z * Wr[128 + lane] +
                xd.w * Wr[192 + lane];
    float attl = att[lane];
    int beg = rs[n];
    int end = (n == NN - 1) ? ETOT : rs[n + 1];
    float acc = 0.f, den = 0.f;
    int base = beg;
    while (base < end) {
        int cnt = end - base;
        if (cnt > 64) cnt = 64;
        int si = (lane < cnt) ? srcs[base + lane] : 0;
        int j = 0;
        for (; j + 2 <= cnt; j += 2) {
            int s0 = __builtin_amdgcn_readlane(si, j);
            int s1 = __builtin_amdgcn_readlane(si, j + 1);
            const float4 xa = *(const float4*)(x + s0 * 4);
            const float4 xb = *(const float4*)(x + s1 * 4);
            float xlsa = xa.x * wl0 + xa.y * wl1 + xa.z * wl2 + xa.w * wl3;
            float xlsb = xb.x * wl0 + xb.y * wl1 + xb.z * wl2 + xb.w * wl3;
            float ta = leaky(xlsa + xrd) * attl;
            float tb = leaky(xlsb + xrd) * attl;
            ta += __shfl_xor(ta, 1); tb += __shfl_xor(tb, 1);
            ta += __shfl_xor(ta, 2); tb += __shfl_xor(tb, 2);
            ta += __shfl_xor(ta, 4); tb += __shfl_xor(tb, 4);
            ta += __shfl_xor(ta, 8); tb += __shfl_xor(tb, 8);
            float exa = __expf(ta), exb = __expf(tb);
            acc += exa * xlsa;
            acc += exb * xlsb;
            den += exa + exb;
        }
        if (j < cnt) {
            int s0 = __builtin_amdgcn_readlane(si, j);
            const float4 xa = *(const float4*)(x + s0 * 4);
            float xlsa = xa.x * wl0 + xa.y * wl1 + xa.z * wl2 + xa.w * wl3;
            float ta = leaky(xlsa + xrd) * attl;
            ta += __shfl_xor(ta, 1);
            ta += __shfl_xor(ta, 2);
            ta += __shfl_xor(ta, 4);
            ta += __shfl_xor(ta, 8);
            float exa = __expf(ta);
            acc += exa * xlsa;
            den += exa;
        }
        base += cnt;
    }
    float v = acc / den + b[lane];
    float s1 = v;
#pragma unroll
    for (int m = 1; m < 64; m <<= 1) s1 += __shfl_xor(s1, m);
    float mu = s1 * (1.f / 64.f);
    float c = v - mu;
    float sq = c * c;
#pragma unroll
    for (int m = 1; m < 64; m <<= 1) sq += __shfl_xor(sq, m);
    float y = c * rsqrtf(sq * (1.f / 64.f) + 1e-5f) * g[lane] + be[lane];
    h[(long long)n * 64 + lane] = y > 0.f ? y : expm1f(y);
}

// ---------------- layer 2 node transform: h[N,64] @ W[64,32] (l and r) ------
__global__ void k_lin2(const float* __restrict__ h, const float* __restrict__ Wl,
                       const float* __restrict__ Wr, float* __restrict__ xl2,
                       float* __restrict__ xr2) {
    __shared__ float wl_s[2048];
    __shared__ float wr_s[2048];
    for (int i = threadIdx.x; i < 2048; i += blockDim.x) {
        wl_s[i] = Wl[i];
        wr_s[i] = Wr[i];
    }
    __syncthreads();
    int t = blockIdx.x * blockDim.x + threadIdx.x;
    if (t >= NN * 32) return;
    int n = t >> 5, j = t & 31;
    const float* hr = h + (long long)n * 64;
    float al = 0.f, ar = 0.f;
#pragma unroll 8
    for (int k = 0; k < 64; ++k) {
        float hv = hr[k];
        al += hv * wl_s[k * 32 + j];
        ar += hv * wr_s[k * 32 + j];
    }
    xl2[(long long)n * 32 + j] = al;
    xr2[(long long)n * 32 + j] = ar;
}

// ------ layer 2 gather: one wave per node; 2 edges/iter via halves, x2 unroll
__global__ void k_gat2(const float* __restrict__ xl2, const float* __restrict__ xr2,
                       const float* __restrict__ att, const int* __restrict__ rs,
                       const int* __restrict__ srcs, const float* __restrict__ b,
                       const float* __restrict__ g, const float* __restrict__ be,
                       float* __restrict__ out) {
    int n = blockIdx.x * (blockDim.x >> 6) + (threadIdx.x >> 6);
    if (n >= NN) return;
    int lane = threadIdx.x & 63;
    int half = lane >> 5, c = lane & 31;
    float xrd = xr2[(long long)n * 32 + c];
    float attl = att[c];
    int beg = rs[n];
    int end = (n == NN - 1) ? ETOT : rs[n + 1];
    float acc = 0.f, den = 0.f;
    int base = beg;
    while (base < end) {
        int cnt = end - base;
        if (cnt > 64) cnt = 64;
        int si = (lane < cnt) ? srcs[base + lane] : 0;
        int nit = (cnt + 1) >> 1;  // pair-iterations
        int j = 0;
        for (; j + 2 <= nit; j += 2) {
            int i0 = j * 2 + half, i1 = (j + 1) * 2 + half;
            bool v0 = i0 < cnt, v1 = i1 < cnt;
            int s0 = __shfl(si, v0 ? i0 : 0);
            int s1 = __shfl(si, v1 ? i1 : 0);
            float xlsa = xl2[(long long)s0 * 32 + c];
            float xlsb = xl2[(long long)s1 * 32 + c];
            float ta = leaky(xlsa + xrd) * attl;
            float tb = leaky(xlsb + xrd) * attl;
            ta += __shfl_xor(ta, 1);  tb += __shfl_xor(tb, 1);
            ta += __shfl_xor(ta, 2);  tb += __shfl_xor(tb, 2);
            ta += __shfl_xor(ta, 4);  tb += __shfl_xor(tb, 4);
            ta += __shfl_xor(ta, 8);  tb += __shfl_xor(tb, 8);
            ta += __shfl_xor(ta, 16); tb += __shfl_xor(tb, 16);
            float exa = v0 ? __expf(ta) : 0.f;
            float exb = v1 ? __expf(tb) : 0.f;
            acc += exa * xlsa;
            acc += exb * xlsb;
            den += exa + exb;
        }
        if (j < nit) {
            int i0 = j * 2 + half;
            bool v0 = i0 < cnt;
            int s0 = __shfl(si, v0 ? i0 : 0);
            float xlsa = xl2[(long long)s0 * 32 + c];
            float ta = leaky(xlsa + xrd) * attl;
            ta += __shfl_xor(ta, 1);
            ta += __shfl_xor(ta, 2);
            ta += __shfl_xor(ta, 4);
            ta += __shfl_xor(ta, 8);
            ta += __shfl_xor(ta, 16);
            float exa = v0 ? __expf(ta) : 0.f;
            acc += exa * xlsa;
            den += exa;
        }
        base += cnt;
    }
    acc += __shfl_xor(acc, 32);
    den += __shfl_xor(den, 32);
    float v = acc / den + b[c];
    float s1 = v;
#pragma unroll
    for (int m = 1; m < 32; m <<= 1) s1 += __shfl_xor(s1, m);
    float mu = s1 * (1.f / 32.f);
    float cc = v - mu;
    float sq = cc * cc;
#pragma unroll
    for (int m = 1; m < 32; m <<= 1) sq += __shfl_xor(sq, m);
    float y = cc * rsqrtf(sq * (1.f / 32.f) + 1e-5f) * g[c] + be[c];
    if (half == 0) out[(long long)n * 32 + c] = y;
}

extern "C" void kernel_launch(void* const* d_in, const int* in_sizes, int n_in,
                              void* d_out, int out_size, void* d_ws, size_t ws_size,
                              hipStream_t stream) {
    const float* x   = (const float*)d_in[0];
    const int*   ei  = (const int*)d_in[1];
    const float* W1l = (const float*)d_in[2];
    const float* W1r = (const float*)d_in[3];
    const float* a1  = (const float*)d_in[4];
    const float* b1  = (const float*)d_in[5];
    const float* g1  = (const float*)d_in[6];
    const float* be1 = (const float*)d_in[7];
    const float* W2l = (const float*)d_in[8];
    const float* W2r = (const float*)d_in[9];
    const float* a2  = (const float*)d_in[10];
    const float* b2  = (const float*)d_in[11];
    const float* g2  = (const float*)d_in[12];
    const float* be2 = (const float*)d_in[13];
    float* out = (float*)d_out;

    float* ws = (float*)d_ws;
    float* h   = ws;             // N*64 floats (layer-1 output; written AFTER CSR)
    float* xl2 = ws + 6400000;   // N*32
    float* xr2 = ws + 9600000;   // N*32
    int2* binned = (int2*)ws;    // E0 pairs = 12.8 MB, aliases h (CSR phase only)
    int* ib        = (int*)(ws + 12800000);
    int* rs        = ib;              // NN
    int* srcs      = ib + 100000;     // ETOT = 1.7M
    int* bcnt      = ib + 1800000;    // NB
    int* boff      = ib + 1800000 + NB;
    int* srcsBase  = ib + 1800000 + 2 * NB;
    int* cursor    = ib + 1800000 + 3 * NB;

    // ---- CSR build via 2-level counting sort ----
    hipMemsetAsync(bcnt, 0, NB * sizeof(int), stream);
    k_bhist<<<256, 256, 0, stream>>>(ei, bcnt);
    k_bscan<<<1, NB, 0, stream>>>(bcnt, boff, srcsBase, cursor);
    k_bin<<<(E0 + CHUNK - 1) / CHUNK, 256, 0, stream>>>(ei, cursor, binned);
    k_bfin<<<NB, 256, 0, stream>>>(binned, bcnt, boff, srcsBase, rs, srcs);

    // ---- layer 1 (xl recomputed from x in-wave) ----
    k_gat1<<<(NN + 3) / 4, 256, 0, stream>>>(x, W1l, W1r, a1, rs, srcs,
                                             b1, g1, be1, h);
    // ---- layer 2 ----
    k_lin2<<<(NN * 32 + 255) / 256, 256, 0, stream>>>(h, W2l, W2r, xl2, xr2);
    k_gat2<<<(NN + 3) / 4, 256, 0, stream>>>(xl2, xr2, a2, rs, srcs,
                                             b2, g2, be2, out);
}

// Round 5
// 228.658 us; speedup vs baseline: 38.9729x; 1.1389x over previous
//
#include <hip/hip_runtime.h>
#include <math.h>

#define NN 100000
#define E0 1600000
#define ETOT (E0 + NN)
#define NEG 0.2f

#define NB 512          // dst buckets
#define BS 196          // nodes per bucket (NB*BS >= NN)
#define CHUNK 4096      // edges per k_bin block
#define PPT 16          // pairs per thread
#define MAXP 4096       // max pairs per bucket (mean 3136, sigma 56)

__device__ __forceinline__ float leaky(float v) { return fmaxf(v, NEG * v); }

// ---- pass A: bucket histogram (LDS-aggregated) -----------------------------
__global__ void k_bhist(const int* __restrict__ ei, int* __restrict__ bcnt) {
    __shared__ int h[NB];
    int tid = threadIdx.x;
    for (int i = tid; i < NB; i += 256) h[i] = 0;
    __syncthreads();
    int stride = gridDim.x * 256;
    for (int e = blockIdx.x * 256 + tid; e < E0; e += stride)
        atomicAdd(&h[ei[E0 + e] / BS], 1);
    __syncthreads();
    for (int i = tid; i < NB; i += 256)
        if (h[i]) atomicAdd(&bcnt[i], h[i]);
}

// ---- pass B: scan bucket counts --------------------------------------------
__global__ void k_bscan(const int* __restrict__ bcnt, int* __restrict__ boff,
                        int* __restrict__ srcsBase, int* __restrict__ cursor) {
    __shared__ int s[NB];
    int tid = threadIdx.x;
    int v = bcnt[tid];
    s[tid] = v;
    __syncthreads();
    for (int off = 1; off < NB; off <<= 1) {
        int t = (tid >= off) ? s[tid - off] : 0;
        __syncthreads();
        s[tid] += t;
        __syncthreads();
    }
    int excl = s[tid] - v;
    boff[tid] = excl;
    cursor[tid] = excl;
    int n0 = tid * BS;
    if (n0 > NN) n0 = NN;
    srcsBase[tid] = excl + n0;  // + self-loops of all earlier nodes
}

// ---- pass C: bin edges into bucket-sorted pair array (run-aggregated) ------
__global__ void k_bin(const int* __restrict__ ei, int* __restrict__ cursor,
                      int2* __restrict__ binned) {
    __shared__ int hist[NB];
    __shared__ int basesh[NB];
    int tid = threadIdx.x;
    long long cbase = (long long)blockIdx.x * CHUNK;
    for (int i = tid; i < NB; i += 256) hist[i] = 0;
    __syncthreads();
    int srcv[PPT], dstv[PPT], rank[PPT], bkt[PPT];
#pragma unroll
    for (int k = 0; k < PPT; ++k) {
        long long e = cbase + k * 256 + tid;
        if (e < E0) {
            int s_ = ei[e];
            int d_ = ei[E0 + e];
            int b = d_ / BS;
            rank[k] = atomicAdd(&hist[b], 1);
            srcv[k] = s_;
            dstv[k] = d_;
            bkt[k] = b;
        } else {
            bkt[k] = -1;
        }
    }
    __syncthreads();
    for (int i = tid; i < NB; i += 256)
        if (hist[i] > 0) basesh[i] = atomicAdd(&cursor[i], hist[i]);
    __syncthreads();
#pragma unroll
    for (int k = 0; k < PPT; ++k)
        if (bkt[k] >= 0) {
            int2 p;
            p.x = srcv[k];
            p.y = dstv[k];
            binned[basesh[bkt[k]] + rank[k]] = p;
        }
}

// ---- pass D: per-bucket finalize: row_start + dst-sorted srcs (coalesced) --
__global__ void k_bfin(const int2* __restrict__ binned, const int* __restrict__ bcnt,
                       const int* __restrict__ boff, const int* __restrict__ srcsBase,
                       int* __restrict__ rs, int* __restrict__ srcs) {
    int b = blockIdx.x;
    int n0 = b * BS;
    if (n0 >= NN) return;
    int nd = NN - n0;
    if (nd > BS) nd = BS;
    int cnt = bcnt[b];
    if (cnt > MAXP) cnt = MAXP;  // statistically impossible; safety
    int base = boff[b];
    int sb = srcsBase[b];
    __shared__ int ldsCnt[256];
    __shared__ int scanA[256];
    __shared__ int rowOffE[256];
    __shared__ int stage[MAXP + BS];
    int tid = threadIdx.x;
    ldsCnt[tid] = 0;
    __syncthreads();
    int srcv[PPT], dl_[PPT], rk_[PPT];
#pragma unroll
    for (int k = 0; k < PPT; ++k) {
        int i = k * 256 + tid;
        if (i < cnt) {
            int2 p = binned[base + i];
            int dl = p.y - n0;
            rk_[k] = atomicAdd(&ldsCnt[dl], 1);
            srcv[k] = p.x;
            dl_[k] = dl;
        } else {
            dl_[k] = -1;
        }
    }
    __syncthreads();
    int v = (tid < nd) ? ldsCnt[tid] + 1 : 0;  // +1 self-loop
    scanA[tid] = v;
    __syncthreads();
    for (int off = 1; off < 256; off <<= 1) {
        int t = (tid >= off) ? scanA[tid - off] : 0;
        __syncthreads();
        scanA[tid] += t;
        __syncthreads();
    }
    rowOffE[tid] = scanA[tid] - v;
    __syncthreads();
    if (tid < nd) {
        int e = rowOffE[tid];
        rs[n0 + tid] = sb + e;
        stage[e] = n0 + tid;  // self-loop occupies first slot
    }
    __syncthreads();
#pragma unroll
    for (int k = 0; k < PPT; ++k)
        if (dl_[k] >= 0) stage[rowOffE[dl_[k]] + 1 + rk_[k]] = srcv[k];
    __syncthreads();
    int tot = cnt + nd;
    for (int i = tid; i < tot; i += 256) srcs[sb + i] = stage[i];
}

// ------ layer 1 gather: lane = (e_i<0..7>, sub<0..7>); 8 edges/iter ---------
// lane owns channels c = sub*8 + j (j=0..7); W1l columns register-resident.
// fused: xr on the fly, shift-free softmax, /den + bias, LN(64), ELU
__global__ void k_gat1(const float* __restrict__ x, const float* __restrict__ Wl,
                       const float* __restrict__ Wr, const float* __restrict__ att,
                       const int* __restrict__ rs, const int* __restrict__ srcs,
                       const float* __restrict__ b, const float* __restrict__ g,
                       const float* __restrict__ be, float* __restrict__ h) {
    int lane = threadIdx.x & 63;
    int wave = (blockIdx.x * blockDim.x + threadIdx.x) >> 6;
    int nwaves = (gridDim.x * blockDim.x) >> 6;
    int e_i = lane >> 3;
    int sub = lane & 7;
    float wl[4][8], wr[4][8], at[8];
#pragma unroll
    for (int k = 0; k < 4; ++k)
#pragma unroll
        for (int j = 0; j < 8; ++j) {
            wl[k][j] = Wl[k * 64 + sub * 8 + j];
            wr[k][j] = Wr[k * 64 + sub * 8 + j];
        }
#pragma unroll
    for (int j = 0; j < 8; ++j) at[j] = att[sub * 8 + j];

    for (int n = wave; n < NN; n += nwaves) {
        const float4 xd = *(const float4*)(x + (long long)n * 4);
        float xrd[8];
#pragma unroll
        for (int j = 0; j < 8; ++j)
            xrd[j] = xd.x * wr[0][j] + xd.y * wr[1][j] + xd.z * wr[2][j] +
                     xd.w * wr[3][j];
        int beg = rs[n];
        int end = (n == NN - 1) ? ETOT : rs[n + 1];
        float acc[8] = {0.f, 0.f, 0.f, 0.f, 0.f, 0.f, 0.f, 0.f};
        float den = 0.f;
        for (int base = beg; base < end; base += 8) {
            int slot = base + e_i;
            bool valid = slot < end;
            int s = srcs[valid ? slot : beg];
            const float4 xa = *(const float4*)(x + (long long)s * 4);
            float xls[8];
            float p = 0.f;
#pragma unroll
            for (int j = 0; j < 8; ++j) {
                float t = xa.x * wl[0][j] + xa.y * wl[1][j] + xa.z * wl[2][j] +
                          xa.w * wl[3][j];
                xls[j] = t;
                float u = t + xrd[j];
                u = fmaxf(u, NEG * u);
                p += u * at[j];
            }
            p += __shfl_xor(p, 1);  // sum halves -> full head logit
            float ex = valid ? __expf(p) : 0.f;
            den += ex;
#pragma unroll
            for (int j = 0; j < 8; ++j) acc[j] += ex * xls[j];
        }
        // reduce over e_i lanes (bits 3..5)
#pragma unroll
        for (int m = 8; m <= 32; m <<= 1) {
#pragma unroll
            for (int j = 0; j < 8; ++j) acc[j] += __shfl_xor(acc[j], m);
            den += __shfl_xor(den, m);
        }
        // lane takes channel cf = sub*8 + e_i (same head as its den)
        float v = acc[0];
#pragma unroll
        for (int j = 1; j < 8; ++j) v = (e_i == j) ? acc[j] : v;
        int cf = sub * 8 + e_i;
        v = v / den + b[cf];
        float s1 = v;
#pragma unroll
        for (int m = 1; m < 64; m <<= 1) s1 += __shfl_xor(s1, m);
        float mu = s1 * (1.f / 64.f);
        float c = v - mu;
        float sq = c * c;
#pragma unroll
        for (int m = 1; m < 64; m <<= 1) sq += __shfl_xor(sq, m);
        float y = c * rsqrtf(sq * (1.f / 64.f) + 1e-5f) * g[cf] + be[cf];
        h[(long long)n * 64 + cf] = y > 0.f ? y : expm1f(y);
    }
}

// ---------------- layer 2 node transform: h[N,64] @ W[64,32] (l and r) ------
__global__ void k_lin2(const float* __restrict__ h, const float* __restrict__ Wl,
                       const float* __restrict__ Wr, float* __restrict__ xl2,
                       float* __restrict__ xr2) {
    __shared__ float wl_s[2048];
    __shared__ float wr_s[2048];
    for (int i = threadIdx.x; i < 2048; i += blockDim.x) {
        wl_s[i] = Wl[i];
        wr_s[i] = Wr[i];
    }
    __syncthreads();
    int t = blockIdx.x * blockDim.x + threadIdx.x;
    if (t >= NN * 32) return;
    int n = t >> 5, j = t & 31;
    const float* hr = h + (long long)n * 64;
    float al = 0.f, ar = 0.f;
#pragma unroll 8
    for (int k = 0; k < 64; ++k) {
        float hv = hr[k];
        al += hv * wl_s[k * 32 + j];
        ar += hv * wr_s[k * 32 + j];
    }
    xl2[(long long)n * 32 + j] = al;
    xr2[(long long)n * 32 + j] = ar;
}

// ------ layer 2 gather: lane = (e_i<0..7>, cg<0..7>); 8 edges/iter ----------
// lane owns channels c = cg*4 + j (j=0..3); gathers 16B of xl2 per edge.
__global__ void k_gat2(const float* __restrict__ xl2, const float* __restrict__ xr2,
                       const float* __restrict__ att, const int* __restrict__ rs,
                       const int* __restrict__ srcs, const float* __restrict__ b,
                       const float* __restrict__ g, const float* __restrict__ be,
                       float* __restrict__ out) {
    int lane = threadIdx.x & 63;
    int wave = (blockIdx.x * blockDim.x + threadIdx.x) >> 6;
    int nwaves = (gridDim.x * blockDim.x) >> 6;
    int e_i = lane >> 3;
    int cg = lane & 7;
    float at[4];
#pragma unroll
    for (int j = 0; j < 4; ++j) at[j] = att[cg * 4 + j];

    for (int n = wave; n < NN; n += nwaves) {
        const float4 xr4 = *(const float4*)(xr2 + (long long)n * 32 + cg * 4);
        float xrd[4] = {xr4.x, xr4.y, xr4.z, xr4.w};
        int beg = rs[n];
        int end = (n == NN - 1) ? ETOT : rs[n + 1];
        float acc[4] = {0.f, 0.f, 0.f, 0.f};
        float den = 0.f;
        for (int base = beg; base < end; base += 8) {
            int slot = base + e_i;
            bool valid = slot < end;
            int s = srcs[valid ? slot : beg];
            const float4 xa = *(const float4*)(xl2 + (long long)s * 32 + cg * 4);
            float xls[4] = {xa.x, xa.y, xa.z, xa.w};
            float p = 0.f;
#pragma unroll
            for (int j = 0; j < 4; ++j) {
                float u = xls[j] + xrd[j];
                u = fmaxf(u, NEG * u);
                p += u * at[j];
            }
            p += __shfl_xor(p, 1);
            p += __shfl_xor(p, 2);
            p += __shfl_xor(p, 4);
            float ex = valid ? __expf(p) : 0.f;
            den += ex;
#pragma unroll
            for (int j = 0; j < 4; ++j) acc[j] += ex * xls[j];
        }
        // reduce over e_i lanes (bits 3..5)
#pragma unroll
        for (int m = 8; m <= 32; m <<= 1) {
#pragma unroll
            for (int j = 0; j < 4; ++j) acc[j] += __shfl_xor(acc[j], m);
            den += __shfl_xor(den, m);
        }
        // lane takes channel cf = cg*4 + (e_i&3); channels duplicated x2
        int e3 = e_i & 3;
        float v = acc[0];
#pragma unroll
        for (int j = 1; j < 4; ++j) v = (e3 == j) ? acc[j] : v;
        int cf = cg * 4 + e3;
        v = v / den + b[cf];
        // LN over 64 lanes; each channel appears exactly twice -> mean/var OK
        float s1 = v;
#pragma unroll
        for (int m = 1; m < 64; m <<= 1) s1 += __shfl_xor(s1, m);
        float mu = s1 * (1.f / 64.f);
        float cc = v - mu;
        float sq = cc * cc;
#pragma unroll
        for (int m = 1; m < 64; m <<= 1) sq += __shfl_xor(sq, m);
        float y = cc * rsqrtf(sq * (1.f / 64.f) + 1e-5f) * g[cf] + be[cf];
        if (e_i < 4) out[(long long)n * 32 + cf] = y;
    }
}

extern "C" void kernel_launch(void* const* d_in, const int* in_sizes, int n_in,
                              void* d_out, int out_size, void* d_ws, size_t ws_size,
                              hipStream_t stream) {
    const float* x   = (const float*)d_in[0];
    const int*   ei  = (const int*)d_in[1];
    const float* W1l = (const float*)d_in[2];
    const float* W1r = (const float*)d_in[3];
    const float* a1  = (const float*)d_in[4];
    const float* b1  = (const float*)d_in[5];
    const float* g1  = (const float*)d_in[6];
    const float* be1 = (const float*)d_in[7];
    const float* W2l = (const float*)d_in[8];
    const float* W2r = (const float*)d_in[9];
    const float* a2  = (const float*)d_in[10];
    const float* b2  = (const float*)d_in[11];
    const float* g2  = (const float*)d_in[12];
    const float* be2 = (const float*)d_in[13];
    float* out = (float*)d_out;

    float* ws = (float*)d_ws;
    float* h   = ws;             // N*64 floats (layer-1 output; written AFTER CSR)
    float* xl2 = ws + 6400000;   // N*32
    float* xr2 = ws + 9600000;   // N*32
    int2* binned = (int2*)ws;    // E0 pairs = 12.8 MB, aliases h (CSR phase only)
    int* ib        = (int*)(ws + 12800000);
    int* rs        = ib;              // NN
    int* srcs      = ib + 100000;     // ETOT = 1.7M
    int* bcnt      = ib + 1800000;    // NB
    int* boff      = ib + 1800000 + NB;
    int* srcsBase  = ib + 1800000 + 2 * NB;
    int* cursor    = ib + 1800000 + 3 * NB;

    // ---- CSR build via 2-level counting sort ----
    hipMemsetAsync(bcnt, 0, NB * sizeof(int), stream);
    k_bhist<<<256, 256, 0, stream>>>(ei, bcnt);
    k_bscan<<<1, NB, 0, stream>>>(bcnt, boff, srcsBase, cursor);
    k_bin<<<(E0 + CHUNK - 1) / CHUNK, 256, 0, stream>>>(ei, cursor, binned);
    k_bfin<<<NB, 256, 0, stream>>>(binned, bcnt, boff, srcsBase, rs, srcs);

    // ---- layer 1 (xl recomputed from x in-wave) ----
    k_gat1<<<1024, 256, 0, stream>>>(x, W1l, W1r, a1, rs, srcs, b1, g1, be1, h);
    // ---- layer 2 ----
    k_lin2<<<(NN * 32 + 255) / 256, 256, 0, stream>>>(h, W2l, W2r, xl2, xr2);
    k_gat2<<<2048, 256, 0, stream>>>(xl2, xr2, a2, rs, srcs, b2, g2, be2, out);
}